// Round 1
// baseline (246.189 us; speedup 1.0000x reference)
//
#include <hip/hip_runtime.h>

// ---------------------------------------------------------------------------
// TrXL block on MI355X. bf16 MFMA for all matmuls, fp32 residual spine.
// Layouts:
//   h1, Q, K, attn_out, h2 : bf16 [B*S=8192, 512]  (heads = col blocks of 64)
//   Vt                     : bf16 [B, H, dh=64, S=2048]  (transposed V)
//   h_ln_post              : fp32 [8192, 512]
//   weights prepped to Bt  : bf16 [N=512][K=512]  (row n = output feature)
// ---------------------------------------------------------------------------

typedef __attribute__((ext_vector_type(8))) short bf16x8;     // MFMA A/B frag
typedef __attribute__((ext_vector_type(4))) float f32x4;      // MFMA C/D frag
typedef __attribute__((ext_vector_type(8))) unsigned short u16x8;

static __device__ __forceinline__ unsigned short f2b(float f) {
    union { float f; unsigned u; } a; a.f = f;
    unsigned r = a.u + 0x7FFFu + ((a.u >> 16) & 1u);   // RNE
    return (unsigned short)(r >> 16);
}

// ---- weight prep: cast to bf16, lay out as Bt[n][k] ------------------------
__global__ __launch_bounds__(256) void prep_weights_k(
    const float* __restrict__ Wq, const float* __restrict__ Wk, const float* __restrict__ Wv,
    const float* __restrict__ Wm, const float* __restrict__ Wo,
    unsigned short* __restrict__ wqT, unsigned short* __restrict__ wkT,
    unsigned short* __restrict__ wvT, unsigned short* __restrict__ wmT,
    unsigned short* __restrict__ woT)
{
    int idx = blockIdx.x * 256 + threadIdx.x;     // idx = n*512 + k
    int n = idx >> 9, k = idx & 511;
    int h = n >> 6, e = n & 63;
    size_t src_qkv = ((size_t)h * 512 + k) * 64 + e;   // Wq[h, k, e]
    wqT[idx] = f2b(Wq[src_qkv]);
    wkT[idx] = f2b(Wk[src_qkv]);
    wvT[idx] = f2b(Wv[src_qkv]);
    wmT[idx] = f2b(Wm[(size_t)k * 512 + n]);
    woT[idx] = f2b(Wo[(size_t)k * 512 + n]);
}

// ---- LayerNorm (fp32 in) -> bf16 out. one wave per 512-row ----------------
__global__ __launch_bounds__(64) void ln_bf16_k(
    const float* __restrict__ X, const float* __restrict__ gam,
    const float* __restrict__ bet, unsigned short* __restrict__ O)
{
    int row = blockIdx.x, lane = threadIdx.x;
    const float4* xr = (const float4*)(X + (size_t)row * 512);
    float4 v0 = xr[lane * 2], v1 = xr[lane * 2 + 1];
    float vv[8] = {v0.x, v0.y, v0.z, v0.w, v1.x, v1.y, v1.z, v1.w};
    float s = 0.f, s2 = 0.f;
    #pragma unroll
    for (int j = 0; j < 8; ++j) { s += vv[j]; s2 += vv[j] * vv[j]; }
    #pragma unroll
    for (int d = 1; d < 64; d <<= 1) { s += __shfl_xor(s, d); s2 += __shfl_xor(s2, d); }
    float mean = s * (1.0f / 512.0f);
    float var  = s2 * (1.0f / 512.0f) - mean * mean;
    float rstd = rsqrtf(var + 1e-5f);
    int c = lane * 8;
    u16x8 o;
    #pragma unroll
    for (int j = 0; j < 8; ++j) o[j] = f2b((vv[j] - mean) * rstd * gam[c + j] + bet[c + j]);
    *(u16x8*)(O + (size_t)row * 512 + c) = o;
}

// ---- MFMA GEMM: C[8192,512] = A[8192,512] * Bt^T, K=512 --------------------
// MODE 0: C = bf16(acc + bias)                      (Q, K projections)
// MODE 1: store transposed into Vt[B,H,64,2048]     (V projection)
// MODE 2: C = f32(acc + bias + aux)                 (Wm proj + residual x)
// MODE 3: C = f32(relu(acc + bias) + aux)           (Wo FC + residual)
template<int MODE>
__global__ __launch_bounds__(256) void gemm512_k(
    const unsigned short* __restrict__ A, const unsigned short* __restrict__ Bt,
    const float* __restrict__ bias, const float* __restrict__ aux,
    void* __restrict__ Cout)
{
    __shared__ unsigned short Al[128][40];   // rows 80B: 16B-aligned row starts
    __shared__ unsigned short Bl[128][40];
    int tid = threadIdx.x;
    int wid = tid >> 6, lane = tid & 63;
    int lr = lane & 15, lg = lane >> 4;
    int m0 = blockIdx.x * 128, n0 = blockIdx.y * 128;
    int wr = (wid >> 1) * 64, wc = (wid & 1) * 64;
    f32x4 acc[4][4] = {};
    int ldr = tid >> 1;             // 0..127
    int ldc = (tid & 1) * 16;       // 0 / 16
    const unsigned short* Ap = A  + (size_t)(m0 + ldr) * 512 + ldc;
    const unsigned short* Bp = Bt + (size_t)(n0 + ldr) * 512 + ldc;
    for (int k0 = 0; k0 < 512; k0 += 32) {
        u16x8 a0 = *(const u16x8*)(Ap + k0);
        u16x8 a1 = *(const u16x8*)(Ap + k0 + 8);
        u16x8 b0 = *(const u16x8*)(Bp + k0);
        u16x8 b1 = *(const u16x8*)(Bp + k0 + 8);
        __syncthreads();                      // prior iter readers done
        *(u16x8*)&Al[ldr][ldc]     = a0;
        *(u16x8*)&Al[ldr][ldc + 8] = a1;
        *(u16x8*)&Bl[ldr][ldc]     = b0;
        *(u16x8*)&Bl[ldr][ldc + 8] = b1;
        __syncthreads();
        bf16x8 af[4], bfr[4];
        #pragma unroll
        for (int m = 0; m < 4; ++m) af[m]  = *(const bf16x8*)&Al[wr + m * 16 + lr][8 * lg];
        #pragma unroll
        for (int n = 0; n < 4; ++n) bfr[n] = *(const bf16x8*)&Bl[wc + n * 16 + lr][8 * lg];
        #pragma unroll
        for (int m = 0; m < 4; ++m)
            #pragma unroll
            for (int n = 0; n < 4; ++n)
                acc[m][n] = __builtin_amdgcn_mfma_f32_16x16x32_bf16(af[m], bfr[n], acc[m][n], 0, 0, 0);
    }
    #pragma unroll
    for (int m = 0; m < 4; ++m)
      #pragma unroll
      for (int n = 0; n < 4; ++n)
        #pragma unroll
        for (int j = 0; j < 4; ++j) {
            int gr = m0 + wr + m * 16 + 4 * lg + j;
            int gc = n0 + wc + n * 16 + lr;
            float v = acc[m][n][j] + bias[gc];
            if (MODE == 0) {
                ((unsigned short*)Cout)[(size_t)gr * 512 + gc] = f2b(v);
            } else if (MODE == 1) {
                int bb = gr >> 11, ss = gr & 2047, hh = gc >> 6, ee = gc & 63;
                ((unsigned short*)Cout)[((size_t)((bb * 8 + hh) * 64 + ee) << 11) + ss] = f2b(v);
            } else if (MODE == 2) {
                ((float*)Cout)[(size_t)gr * 512 + gc] = v + aux[(size_t)gr * 512 + gc];
            } else {
                float r = v > 0.0f ? v : 0.0f;
                ((float*)Cout)[(size_t)gr * 512 + gc] = r + aux[(size_t)gr * 512 + gc];
            }
        }
}

// ---- flash attention: 128 Q-rows/block (4 waves x 32 rows), KV tile 64 -----
__global__ __launch_bounds__(256) void attn_k(
    const unsigned short* __restrict__ Q, const unsigned short* __restrict__ K,
    const unsigned short* __restrict__ Vt, unsigned short* __restrict__ O)
{
    __shared__ unsigned short Kl[64][72];        // [t][e]
    __shared__ unsigned short Vl[64][72];        // [e][t]
    __shared__ unsigned short Pl[4][32][72];     // per-wave P re-layout
    int tid = threadIdx.x, wid = tid >> 6, lane = tid & 63;
    int lr = lane & 15, lg = lane >> 4;
    int bh = blockIdx.y, b = bh >> 3, h = bh & 7;
    int q0 = blockIdx.x * 128;
    const unsigned short* Qb = Q  + (size_t)b * 2048 * 512 + h * 64;
    const unsigned short* Kb = K  + (size_t)b * 2048 * 512 + h * 64;
    const unsigned short* Vb = Vt + (size_t)(b * 8 + h) * 64 * 2048;

    bf16x8 qf[2][2];
    #pragma unroll
    for (int m = 0; m < 2; ++m)
      #pragma unroll
      for (int kk = 0; kk < 2; ++kk)
        qf[m][kk] = *(const bf16x8*)(Qb + (size_t)(q0 + wid * 32 + m * 16 + lr) * 512 + kk * 32 + 8 * lg);

    f32x4 acc_o[2][4] = {};
    float m_run[2][4], l_run[2][4];
    #pragma unroll
    for (int m = 0; m < 2; ++m)
      #pragma unroll
      for (int j = 0; j < 4; ++j) { m_run[m][j] = -1e30f; l_run[m][j] = 0.0f; }

    int krow = tid >> 2, kcol = (tid & 3) * 16;
    for (int t0 = 0; t0 < 2048; t0 += 64) {
        u16x8 kv0 = *(const u16x8*)(Kb + (size_t)(t0 + krow) * 512 + kcol);
        u16x8 kv1 = *(const u16x8*)(Kb + (size_t)(t0 + krow) * 512 + kcol + 8);
        u16x8 vv0 = *(const u16x8*)(Vb + (size_t)krow * 2048 + t0 + kcol);
        u16x8 vv1 = *(const u16x8*)(Vb + (size_t)krow * 2048 + t0 + kcol + 8);
        __syncthreads();
        *(u16x8*)&Kl[krow][kcol]     = kv0;
        *(u16x8*)&Kl[krow][kcol + 8] = kv1;
        *(u16x8*)&Vl[krow][kcol]     = vv0;
        *(u16x8*)&Vl[krow][kcol + 8] = vv1;
        __syncthreads();

        // S = Q K^T / 8
        f32x4 sc[2][4];
        #pragma unroll
        for (int m = 0; m < 2; ++m)
          #pragma unroll
          for (int n = 0; n < 4; ++n) sc[m][n] = (f32x4){0.f, 0.f, 0.f, 0.f};
        #pragma unroll
        for (int n = 0; n < 4; ++n) {
            bf16x8 kf0 = *(const bf16x8*)&Kl[n * 16 + lr][8 * lg];
            bf16x8 kf1 = *(const bf16x8*)&Kl[n * 16 + lr][32 + 8 * lg];
            #pragma unroll
            for (int m = 0; m < 2; ++m) {
                sc[m][n] = __builtin_amdgcn_mfma_f32_16x16x32_bf16(qf[m][0], kf0, sc[m][n], 0, 0, 0);
                sc[m][n] = __builtin_amdgcn_mfma_f32_16x16x32_bf16(qf[m][1], kf1, sc[m][n], 0, 0, 0);
            }
        }

        // online softmax (rows: m in {0,1}, j in {0..3}; cols spread over 16-lane group)
        #pragma unroll
        for (int m = 0; m < 2; ++m)
          #pragma unroll
          for (int j = 0; j < 4; ++j) {
            float mx = -1e30f;
            #pragma unroll
            for (int n = 0; n < 4; ++n) { sc[m][n][j] *= 0.125f; mx = fmaxf(mx, sc[m][n][j]); }
            #pragma unroll
            for (int d = 1; d < 16; d <<= 1) mx = fmaxf(mx, __shfl_xor(mx, d));
            float mnew  = fmaxf(m_run[m][j], mx);
            float alpha = exp2f((m_run[m][j] - mnew) * 1.44269504f);
            m_run[m][j] = mnew;
            float rs = 0.0f;
            #pragma unroll
            for (int n = 0; n < 4; ++n) {
                float p = exp2f((sc[m][n][j] - mnew) * 1.44269504f);
                sc[m][n][j] = p; rs += p;
            }
            #pragma unroll
            for (int d = 1; d < 16; d <<= 1) rs += __shfl_xor(rs, d);
            l_run[m][j] = l_run[m][j] * alpha + rs;
            #pragma unroll
            for (int n = 0; n < 4; ++n) acc_o[m][n][j] *= alpha;
          }

        // P -> LDS (C-frag layout -> A-frag layout round trip), then P @ V
        #pragma unroll
        for (int m = 0; m < 2; ++m)
          #pragma unroll
          for (int n = 0; n < 4; ++n)
            #pragma unroll
            for (int j = 0; j < 4; ++j)
                Pl[wid][m * 16 + 4 * lg + j][n * 16 + lr] = f2b(sc[m][n][j]);
        #pragma unroll
        for (int kt = 0; kt < 2; ++kt) {
            bf16x8 pf[2], vf[4];
            #pragma unroll
            for (int m = 0; m < 2; ++m) pf[m] = *(const bf16x8*)&Pl[wid][m * 16 + lr][kt * 32 + 8 * lg];
            #pragma unroll
            for (int n = 0; n < 4; ++n) vf[n] = *(const bf16x8*)&Vl[n * 16 + lr][kt * 32 + 8 * lg];
            #pragma unroll
            for (int m = 0; m < 2; ++m)
              #pragma unroll
              for (int n = 0; n < 4; ++n)
                acc_o[m][n] = __builtin_amdgcn_mfma_f32_16x16x32_bf16(pf[m], vf[n], acc_o[m][n], 0, 0, 0);
        }
    }

    #pragma unroll
    for (int m = 0; m < 2; ++m)
      #pragma unroll
      for (int n = 0; n < 4; ++n)
        #pragma unroll
        for (int j = 0; j < 4; ++j) {
            int row = q0 + wid * 32 + m * 16 + 4 * lg + j;
            float v = acc_o[m][n][j] / l_run[m][j];
            O[(size_t)(b * 2048 + row) * 512 + h * 64 + n * 16 + lr] = f2b(v);
        }
}

// ---------------------------------------------------------------------------
extern "C" void kernel_launch(void* const* d_in, const int* in_sizes, int n_in,
                              void* d_out, int out_size, void* d_ws, size_t ws_size,
                              hipStream_t stream)
{
    const float* x  = (const float*)d_in[0];
    const float* g1 = (const float*)d_in[1];
    const float* b1 = (const float*)d_in[2];
    const float* Wq = (const float*)d_in[3];
    const float* bq = (const float*)d_in[4];
    const float* Wk = (const float*)d_in[5];
    const float* bk = (const float*)d_in[6];
    const float* Wv = (const float*)d_in[7];
    const float* bv = (const float*)d_in[8];
    const float* Wm = (const float*)d_in[9];
    const float* bm = (const float*)d_in[10];
    const float* g2 = (const float*)d_in[11];
    const float* b2 = (const float*)d_in[12];
    const float* Wo = (const float*)d_in[13];
    const float* bo = (const float*)d_in[14];
    float* out = (float*)d_out;

    char* ws = (char*)d_ws;
    const size_t EB = (size_t)8192 * 512 * 2;   // bf16 activation bytes
    unsigned short* h1  = (unsigned short*)(ws);
    unsigned short* qb  = (unsigned short*)(ws + EB);
    unsigned short* kb  = (unsigned short*)(ws + 2 * EB);
    unsigned short* vtb = (unsigned short*)(ws + 3 * EB);
    unsigned short* ao  = (unsigned short*)(ws + 4 * EB);
    unsigned short* h2  = (unsigned short*)(ws + 5 * EB);
    float*          hlp = (float*)(ws + 6 * EB);               // fp32, 2*EB bytes
    unsigned short* wqT = (unsigned short*)(ws + 8 * EB);
    unsigned short* wkT = wqT + 512 * 512;
    unsigned short* wvT = wkT + 512 * 512;
    unsigned short* wmT = wvT + 512 * 512;
    unsigned short* woT = wmT + 512 * 512;

    prep_weights_k<<<1024, 256, 0, stream>>>(Wq, Wk, Wv, Wm, Wo, wqT, wkT, wvT, wmT, woT);
    ln_bf16_k<<<8192, 64, 0, stream>>>(x, g1, b1, h1);
    gemm512_k<0><<<dim3(64, 4), 256, 0, stream>>>(h1, wqT, bq, nullptr, qb);
    gemm512_k<0><<<dim3(64, 4), 256, 0, stream>>>(h1, wkT, bk, nullptr, kb);
    gemm512_k<1><<<dim3(64, 4), 256, 0, stream>>>(h1, wvT, bv, nullptr, vtb);
    attn_k<<<dim3(16, 32), 256, 0, stream>>>(qb, kb, vtb, ao);
    gemm512_k<2><<<dim3(64, 4), 256, 0, stream>>>(ao, wmT, bm, x, hlp);
    ln_bf16_k<<<8192, 64, 0, stream>>>(hlp, g2, b2, h2);
    gemm512_k<3><<<dim3(64, 4), 256, 0, stream>>>(h2, woT, bo, hlp, out);
}

// Round 2
// 181.385 us; speedup vs baseline: 1.3573x; 1.3573x over previous
//
#include <hip/hip_runtime.h>
#include <hip/hip_bf16.h>

// ---------------------------------------------------------------------------
// TrXL block on MI355X. bf16 MFMA for all matmuls, fp32 residual spine.
//   h1, Q, K, attn_out, h2 : bf16 [B*S=8192, 512]
//   Vt                     : bf16 [B, H, dh=64, S=2048]
//   h_ln_post              : fp32 [8192, 512]
//   weights prepped to Bt  : bf16 [N=512][K=512]
// attn2_k: swapped-QK^T 32x32x16 flash attention (m214-style, D=64).
// ---------------------------------------------------------------------------

typedef __attribute__((ext_vector_type(8))) short bf16x8;
typedef __attribute__((ext_vector_type(4))) float f32x4;
typedef __attribute__((ext_vector_type(16))) float f32x16;
typedef __attribute__((ext_vector_type(8))) unsigned short u16x8;

typedef union { bf16x8 v; unsigned u[4]; u16x8 s; } frag_u;

static __device__ __forceinline__ unsigned short f2b(float f) {
    union { float f; unsigned u; } a; a.f = f;
    unsigned r = a.u + 0x7FFFu + ((a.u >> 16) & 1u);   // RNE
    return (unsigned short)(r >> 16);
}
static __device__ __forceinline__ float b2f(unsigned short u) {
    union { unsigned u; float f; } c; c.u = ((unsigned)u) << 16; return c.f;
}
static __device__ __forceinline__ unsigned pack_bf16(float lo, float hi) {
    __hip_bfloat162 p = __float22bfloat162_rn(make_float2(lo, hi));
    unsigned r; __builtin_memcpy(&r, &p, 4); return r;
}
// permlane32_swap: new_x = {a[0:31], b[0:31]}, new_y = {a[32:63], b[32:63]}
static __device__ __forceinline__ void swap32(int hi, unsigned a, unsigned b,
                                              unsigned& x, unsigned& y) {
#if __has_builtin(__builtin_amdgcn_permlane32_swap)
    typedef __attribute__((ext_vector_type(2))) int i32x2;
    i32x2 r = __builtin_amdgcn_permlane32_swap((int)a, (int)b, false, false);
    x = (unsigned)r[0]; y = (unsigned)r[1];
#else
    unsigned ta = (unsigned)__shfl_xor((int)a, 32);
    unsigned tb = (unsigned)__shfl_xor((int)b, 32);
    x = hi ? tb : a;
    y = hi ? b : ta;
#endif
}

// ---- weight prep ----------------------------------------------------------
__global__ __launch_bounds__(256) void prep_weights_k(
    const float* __restrict__ Wq, const float* __restrict__ Wk, const float* __restrict__ Wv,
    const float* __restrict__ Wm, const float* __restrict__ Wo,
    unsigned short* __restrict__ wqT, unsigned short* __restrict__ wkT,
    unsigned short* __restrict__ wvT, unsigned short* __restrict__ wmT,
    unsigned short* __restrict__ woT)
{
    int idx = blockIdx.x * 256 + threadIdx.x;     // idx = n*512 + k
    int n = idx >> 9, k = idx & 511;
    int h = n >> 6, e = n & 63;
    size_t src_qkv = ((size_t)h * 512 + k) * 64 + e;
    wqT[idx] = f2b(Wq[src_qkv]);
    wkT[idx] = f2b(Wk[src_qkv]);
    wvT[idx] = f2b(Wv[src_qkv]);
    wmT[idx] = f2b(Wm[(size_t)k * 512 + n]);
    woT[idx] = f2b(Wo[(size_t)k * 512 + n]);
}

// ---- LayerNorm ------------------------------------------------------------
__global__ __launch_bounds__(64) void ln_bf16_k(
    const float* __restrict__ X, const float* __restrict__ gam,
    const float* __restrict__ bet, unsigned short* __restrict__ O)
{
    int row = blockIdx.x, lane = threadIdx.x;
    const float4* xr = (const float4*)(X + (size_t)row * 512);
    float4 v0 = xr[lane * 2], v1 = xr[lane * 2 + 1];
    float vv[8] = {v0.x, v0.y, v0.z, v0.w, v1.x, v1.y, v1.z, v1.w};
    float s = 0.f, s2 = 0.f;
    #pragma unroll
    for (int j = 0; j < 8; ++j) { s += vv[j]; s2 += vv[j] * vv[j]; }
    #pragma unroll
    for (int d = 1; d < 64; d <<= 1) { s += __shfl_xor(s, d); s2 += __shfl_xor(s2, d); }
    float mean = s * (1.0f / 512.0f);
    float var  = s2 * (1.0f / 512.0f) - mean * mean;
    float rstd = rsqrtf(var + 1e-5f);
    int c = lane * 8;
    u16x8 o;
    #pragma unroll
    for (int j = 0; j < 8; ++j) o[j] = f2b((vv[j] - mean) * rstd * gam[c + j] + bet[c + j]);
    *(u16x8*)(O + (size_t)row * 512 + c) = o;
}

// ---- MFMA GEMM: C[8192,512] = A[8192,512] * Bt^T --------------------------
template<int MODE>
__global__ __launch_bounds__(256) void gemm512_k(
    const unsigned short* __restrict__ A, const unsigned short* __restrict__ Bt,
    const float* __restrict__ bias, const float* __restrict__ aux,
    void* __restrict__ Cout)
{
    __shared__ unsigned short Al[128][40];
    __shared__ unsigned short Bl[128][40];
    int tid = threadIdx.x;
    int wid = tid >> 6, lane = tid & 63;
    int lr = lane & 15, lg = lane >> 4;
    int m0 = blockIdx.x * 128, n0 = blockIdx.y * 128;
    int wr = (wid >> 1) * 64, wc = (wid & 1) * 64;
    f32x4 acc[4][4] = {};
    int ldr = tid >> 1;
    int ldc = (tid & 1) * 16;
    const unsigned short* Ap = A  + (size_t)(m0 + ldr) * 512 + ldc;
    const unsigned short* Bp = Bt + (size_t)(n0 + ldr) * 512 + ldc;
    for (int k0 = 0; k0 < 512; k0 += 32) {
        u16x8 a0 = *(const u16x8*)(Ap + k0);
        u16x8 a1 = *(const u16x8*)(Ap + k0 + 8);
        u16x8 b0 = *(const u16x8*)(Bp + k0);
        u16x8 b1 = *(const u16x8*)(Bp + k0 + 8);
        __syncthreads();
        *(u16x8*)&Al[ldr][ldc]     = a0;
        *(u16x8*)&Al[ldr][ldc + 8] = a1;
        *(u16x8*)&Bl[ldr][ldc]     = b0;
        *(u16x8*)&Bl[ldr][ldc + 8] = b1;
        __syncthreads();
        bf16x8 af[4], bfr[4];
        #pragma unroll
        for (int m = 0; m < 4; ++m) af[m]  = *(const bf16x8*)&Al[wr + m * 16 + lr][8 * lg];
        #pragma unroll
        for (int n = 0; n < 4; ++n) bfr[n] = *(const bf16x8*)&Bl[wc + n * 16 + lr][8 * lg];
        #pragma unroll
        for (int m = 0; m < 4; ++m)
            #pragma unroll
            for (int n = 0; n < 4; ++n)
                acc[m][n] = __builtin_amdgcn_mfma_f32_16x16x32_bf16(af[m], bfr[n], acc[m][n], 0, 0, 0);
    }
    #pragma unroll
    for (int m = 0; m < 4; ++m)
      #pragma unroll
      for (int n = 0; n < 4; ++n)
        #pragma unroll
        for (int j = 0; j < 4; ++j) {
            int gr = m0 + wr + m * 16 + 4 * lg + j;
            int gc = n0 + wc + n * 16 + lr;
            float v = acc[m][n][j] + bias[gc];
            if (MODE == 0) {
                ((unsigned short*)Cout)[(size_t)gr * 512 + gc] = f2b(v);
            } else if (MODE == 1) {
                int bb = gr >> 11, ss = gr & 2047, hh = gc >> 6, ee = gc & 63;
                ((unsigned short*)Cout)[((size_t)((bb * 8 + hh) * 64 + ee) << 11) + ss] = f2b(v);
            } else if (MODE == 2) {
                ((float*)Cout)[(size_t)gr * 512 + gc] = v + aux[(size_t)gr * 512 + gc];
            } else {
                float r = v > 0.0f ? v : 0.0f;
                ((float*)Cout)[(size_t)gr * 512 + gc] = r + aux[(size_t)gr * 512 + gc];
            }
        }
}

// ---- flash attention, swapped-QK^T 32x32x16 -------------------------------
// 4 waves/block, 32 q-rows/wave, KVBLK=64. Lane owns q = lane&31.
// K tile LDS: token t,d -> row (t&31), colbyte ((t>>5)*128 + 2d) ^ ((t&15)<<4)
// V tile LDS: e,tok     -> row (e&31), colbyte ((e>>5)*128 + 2tok)^((e&15)<<4)
__global__ __launch_bounds__(256) void attn2_k(
    const unsigned short* __restrict__ Q, const unsigned short* __restrict__ K,
    const unsigned short* __restrict__ Vt, unsigned short* __restrict__ O)
{
    __shared__ unsigned short Kl[4096];   // 8 KB
    __shared__ unsigned short Vl[4096];   // 8 KB
    const int tid  = threadIdx.x;
    const int lane = tid & 63;
    const int q31  = lane & 31;          // q (scores) / token-row / e-row
    const int hi   = lane >> 5;
    const int wid  = tid >> 6;
    const int bh = blockIdx.y, b = bh >> 3, h = bh & 7;
    const int q0 = blockIdx.x * 128 + wid * 32;

    const unsigned short* Qb = Q  + (size_t)b * 2048 * 512 + h * 64;
    const unsigned short* Kb = K  + (size_t)b * 2048 * 512 + h * 64;
    const unsigned short* Vb = Vt + (size_t)(b * 8 + h) * 64 * 2048;

    // Q B-frags, pre-scaled by 1/sqrt(dh) * log2(e)
    frag_u qf[4];
    const float qs = 0.125f * 1.44269504f;
    #pragma unroll
    for (int ds = 0; ds < 4; ++ds) {
        u16x8 raw = *(const u16x8*)(Qb + (size_t)(q0 + q31) * 512 + ds * 16 + hi * 8);
        #pragma unroll
        for (int i = 0; i < 4; ++i)
            qf[ds].u[i] = pack_bf16(b2f(raw[2 * i]) * qs, b2f(raw[2 * i + 1]) * qs);
    }

    // staging map: thread covers rows idx0 and idx0+32, segment seg0 (16B)
    const int idx0 = tid >> 3, seg0 = tid & 7;
    const unsigned off0 = (unsigned)(idx0 * 256 + ((seg0 * 16) ^ ((idx0 & 15) << 4)));
    const unsigned off1 = (unsigned)(idx0 * 256 + ((128 + seg0 * 16) ^ ((idx0 & 15) << 4)));
    const int swz = (q31 & 15) << 4;

    u16x8 ldK0, ldK1, ldV0, ldV1;
    auto LOADS = [&](int t0) {
        ldK0 = *(const u16x8*)(Kb + (size_t)(t0 + idx0) * 512 + seg0 * 8);
        ldK1 = *(const u16x8*)(Kb + (size_t)(t0 + idx0 + 32) * 512 + seg0 * 8);
        ldV0 = *(const u16x8*)(Vb + (size_t)idx0 * 2048 + t0 + seg0 * 8);
        ldV1 = *(const u16x8*)(Vb + (size_t)(idx0 + 32) * 2048 + t0 + seg0 * 8);
    };

    f32x16 acc0, acc1;
    #pragma unroll
    for (int r = 0; r < 16; ++r) { acc0[r] = 0.0f; acc1[r] = 0.0f; }
    float m_run = -1e30f, l_run = 0.0f;

    LOADS(0);
    for (int t0 = 0; t0 < 2048; t0 += 64) {
        __syncthreads();                      // prev-tile readers done
        *(u16x8*)((char*)Kl + off0) = ldK0;
        *(u16x8*)((char*)Kl + off1) = ldK1;
        *(u16x8*)((char*)Vl + off0) = ldV0;
        *(u16x8*)((char*)Vl + off1) = ldV1;
        __syncthreads();
        if (t0 + 64 < 2048) LOADS(t0 + 64);   // hide HBM under compute

        // S^T = K · Q^T  (log2-scaled). s0: tokens t0..t0+31, s1: +32..63
        f32x16 s0, s1;
        #pragma unroll
        for (int r = 0; r < 16; ++r) { s0[r] = 0.0f; s1[r] = 0.0f; }
        #pragma unroll
        for (int ds = 0; ds < 4; ++ds) {
            bf16x8 k0 = *(const bf16x8*)((char*)Kl + q31 * 256 + ((ds * 32 + hi * 16) ^ swz));
            bf16x8 k1 = *(const bf16x8*)((char*)Kl + q31 * 256 + ((128 + ds * 32 + hi * 16) ^ swz));
            s0 = __builtin_amdgcn_mfma_f32_32x32x16_bf16(k0, qf[ds].v, s0, 0, 0, 0);
            s1 = __builtin_amdgcn_mfma_f32_32x32x16_bf16(k1, qf[ds].v, s1, 0, 0, 0);
        }

        // online softmax, lane-local row (q = q31); defer-max THR=11 (log2)
        float tmax = -1e30f;
        #pragma unroll
        for (int r = 0; r < 16; ++r) tmax = fmaxf(tmax, fmaxf(s0[r], s1[r]));
        tmax = fmaxf(tmax, __shfl_xor(tmax, 32));
        if (__any(tmax > m_run + 11.0f)) {
            float mnew  = fmaxf(m_run, tmax);
            float alpha = exp2f(m_run - mnew);
            m_run = mnew;
            l_run *= alpha;
            #pragma unroll
            for (int r = 0; r < 16; ++r) {
                int cr = (r & 3) + 8 * (r >> 2) + 4 * hi;   // q-row of this reg
                float ar = __shfl(alpha, cr);
                acc0[r] *= ar; acc1[r] *= ar;
            }
        }
        float rsum = 0.0f;
        #pragma unroll
        for (int r = 0; r < 16; ++r) {
            s0[r] = exp2f(s0[r] - m_run); rsum += s0[r];
            s1[r] = exp2f(s1[r] - m_run); rsum += s1[r];
        }
        rsum += __shfl_xor(rsum, 32);
        l_run += rsum;

        // P C-frag -> A-frags, in-register (cvt_pk pairs + permlane32_swap)
        frag_u pa[4];
        #pragma unroll
        for (int g = 0; g < 2; ++g) {
            unsigned A0 = pack_bf16(s0[8 * g + 0], s0[8 * g + 1]);
            unsigned A1 = pack_bf16(s0[8 * g + 2], s0[8 * g + 3]);
            unsigned A2 = pack_bf16(s0[8 * g + 4], s0[8 * g + 5]);
            unsigned A3 = pack_bf16(s0[8 * g + 6], s0[8 * g + 7]);
            swap32(hi, A0, A2, pa[g].u[0], pa[g].u[2]);
            swap32(hi, A1, A3, pa[g].u[1], pa[g].u[3]);
            unsigned B0 = pack_bf16(s1[8 * g + 0], s1[8 * g + 1]);
            unsigned B1 = pack_bf16(s1[8 * g + 2], s1[8 * g + 3]);
            unsigned B2 = pack_bf16(s1[8 * g + 4], s1[8 * g + 5]);
            unsigned B3 = pack_bf16(s1[8 * g + 6], s1[8 * g + 7]);
            swap32(hi, B0, B2, pa[2 + g].u[0], pa[2 + g].u[2]);
            swap32(hi, B1, B3, pa[2 + g].u[1], pa[2 + g].u[3]);
        }

        // O += P · V   (A = P rows=q, B = Vt rows=e)
        #pragma unroll
        for (int ks = 0; ks < 4; ++ks) {
            bf16x8 v0 = *(const bf16x8*)((char*)Vl + q31 * 256 + ((ks * 32 + hi * 16) ^ swz));
            bf16x8 v1 = *(const bf16x8*)((char*)Vl + q31 * 256 + ((128 + ks * 32 + hi * 16) ^ swz));
            acc0 = __builtin_amdgcn_mfma_f32_32x32x16_bf16(pa[ks].v, v0, acc0, 0, 0, 0);
            acc1 = __builtin_amdgcn_mfma_f32_32x32x16_bf16(pa[ks].v, v1, acc1, 0, 0, 0);
        }
    }

    float linv = 1.0f / l_run;
    #pragma unroll
    for (int r = 0; r < 16; ++r) {
        int cr = (r & 3) + 8 * (r >> 2) + 4 * hi;
        float li = __shfl(linv, cr);
        size_t rowoff = (size_t)(b * 2048 + q0 + cr) * 512 + h * 64 + q31;
        O[rowoff]      = f2b(acc0[r] * li);
        O[rowoff + 32] = f2b(acc1[r] * li);
    }
}

// ---------------------------------------------------------------------------
extern "C" void kernel_launch(void* const* d_in, const int* in_sizes, int n_in,
                              void* d_out, int out_size, void* d_ws, size_t ws_size,
                              hipStream_t stream)
{
    const float* x  = (const float*)d_in[0];
    const float* g1 = (const float*)d_in[1];
    const float* b1 = (const float*)d_in[2];
    const float* Wq = (const float*)d_in[3];
    const float* bq = (const float*)d_in[4];
    const float* Wk = (const float*)d_in[5];
    const float* bk = (const float*)d_in[6];
    const float* Wv = (const float*)d_in[7];
    const float* bv = (const float*)d_in[8];
    const float* Wm = (const float*)d_in[9];
    const float* bm = (const float*)d_in[10];
    const float* g2 = (const float*)d_in[11];
    const float* b2 = (const float*)d_in[12];
    const float* Wo = (const float*)d_in[13];
    const float* bo = (const float*)d_in[14];
    float* out = (float*)d_out;

    char* ws = (char*)d_ws;
    const size_t EB = (size_t)8192 * 512 * 2;
    unsigned short* h1  = (unsigned short*)(ws);
    unsigned short* qb  = (unsigned short*)(ws + EB);
    unsigned short* kb  = (unsigned short*)(ws + 2 * EB);
    unsigned short* vtb = (unsigned short*)(ws + 3 * EB);
    unsigned short* ao  = (unsigned short*)(ws + 4 * EB);
    unsigned short* h2  = (unsigned short*)(ws + 5 * EB);
    float*          hlp = (float*)(ws + 6 * EB);
    unsigned short* wqT = (unsigned short*)(ws + 8 * EB);
    unsigned short* wkT = wqT + 512 * 512;
    unsigned short* wvT = wkT + 512 * 512;
    unsigned short* wmT = wvT + 512 * 512;
    unsigned short* woT = wmT + 512 * 512;

    prep_weights_k<<<1024, 256, 0, stream>>>(Wq, Wk, Wv, Wm, Wo, wqT, wkT, wvT, wmT, woT);
    ln_bf16_k<<<8192, 64, 0, stream>>>(x, g1, b1, h1);
    gemm512_k<0><<<dim3(64, 4), 256, 0, stream>>>(h1, wqT, bq, nullptr, qb);
    gemm512_k<0><<<dim3(64, 4), 256, 0, stream>>>(h1, wkT, bk, nullptr, kb);
    gemm512_k<1><<<dim3(64, 4), 256, 0, stream>>>(h1, wvT, bv, nullptr, vtb);
    attn2_k<<<dim3(16, 32), 256, 0, stream>>>(qb, kb, vtb, ao);
    gemm512_k<2><<<dim3(64, 4), 256, 0, stream>>>(ao, wmT, bm, x, hlp);
    ln_bf16_k<<<8192, 64, 0, stream>>>(hlp, g2, b2, h2);
    gemm512_k<3><<<dim3(64, 4), 256, 0, stream>>>(h2, woT, bo, hlp, out);
}

// Round 3
// 165.958 us; speedup vs baseline: 1.4834x; 1.0930x over previous
//
#include <hip/hip_runtime.h>
#include <hip/hip_bf16.h>

// ---------------------------------------------------------------------------
// TrXL block on MI355X. bf16 MFMA everywhere, fp32 residual spine.
//   h1, Q, K, attn_out, h2 : bf16 [B*S=8192, 512]
//   Vt                     : bf16 [B, H, dh=64, S=2048]
//   h_ln_post              : fp32 [8192, 512]
//   weights prepped to Bt  : bf16 [N][K=512]  (QKV stacked to N=1536)
// attn3_k: swapped-QK^T 32x32x16 flash attention, KV-split wave pairs.
// ---------------------------------------------------------------------------

typedef __attribute__((ext_vector_type(8))) short bf16x8;
typedef __attribute__((ext_vector_type(4))) float f32x4;
typedef __attribute__((ext_vector_type(16))) float f32x16;
typedef __attribute__((ext_vector_type(8))) unsigned short u16x8;

typedef union { bf16x8 v; unsigned u[4]; u16x8 s; } frag_u;

static __device__ __forceinline__ unsigned short f2b(float f) {
    union { float f; unsigned u; } a; a.f = f;
    unsigned r = a.u + 0x7FFFu + ((a.u >> 16) & 1u);   // RNE
    return (unsigned short)(r >> 16);
}
static __device__ __forceinline__ float b2f(unsigned short u) {
    union { unsigned u; float f; } c; c.u = ((unsigned)u) << 16; return c.f;
}
static __device__ __forceinline__ unsigned pack_bf16(float lo, float hi) {
    __hip_bfloat162 p = __float22bfloat162_rn(make_float2(lo, hi));
    unsigned r; __builtin_memcpy(&r, &p, 4); return r;
}
// permlane32_swap: new_x = {a[0:31], b[0:31]}, new_y = {a[32:63], b[32:63]}
static __device__ __forceinline__ void swap32(int hi, unsigned a, unsigned b,
                                              unsigned& x, unsigned& y) {
#if __has_builtin(__builtin_amdgcn_permlane32_swap)
    typedef __attribute__((ext_vector_type(2))) int i32x2;
    i32x2 r = __builtin_amdgcn_permlane32_swap((int)a, (int)b, false, false);
    x = (unsigned)r[0]; y = (unsigned)r[1];
#else
    unsigned ta = (unsigned)__shfl_xor((int)a, 32);
    unsigned tb = (unsigned)__shfl_xor((int)b, 32);
    x = hi ? tb : a;
    y = hi ? b : ta;
#endif
}

// ---- weight prep ----------------------------------------------------------
__global__ __launch_bounds__(256) void prep_weights_k(
    const float* __restrict__ Wq, const float* __restrict__ Wk, const float* __restrict__ Wv,
    const float* __restrict__ Wm, const float* __restrict__ Wo,
    unsigned short* __restrict__ wqT, unsigned short* __restrict__ wkT,
    unsigned short* __restrict__ wvT, unsigned short* __restrict__ wmT,
    unsigned short* __restrict__ woT)
{
    int idx = blockIdx.x * 256 + threadIdx.x;     // idx = n*512 + k
    int n = idx >> 9, k = idx & 511;
    int h = n >> 6, e = n & 63;
    size_t src_qkv = ((size_t)h * 512 + k) * 64 + e;
    wqT[idx] = f2b(Wq[src_qkv]);
    wkT[idx] = f2b(Wk[src_qkv]);
    wvT[idx] = f2b(Wv[src_qkv]);
    wmT[idx] = f2b(Wm[(size_t)k * 512 + n]);
    woT[idx] = f2b(Wo[(size_t)k * 512 + n]);
}

// ---- LayerNorm ------------------------------------------------------------
__global__ __launch_bounds__(64) void ln_bf16_k(
    const float* __restrict__ X, const float* __restrict__ gam,
    const float* __restrict__ bet, unsigned short* __restrict__ O)
{
    int row = blockIdx.x, lane = threadIdx.x;
    const float4* xr = (const float4*)(X + (size_t)row * 512);
    float4 v0 = xr[lane * 2], v1 = xr[lane * 2 + 1];
    float vv[8] = {v0.x, v0.y, v0.z, v0.w, v1.x, v1.y, v1.z, v1.w};
    float s = 0.f, s2 = 0.f;
    #pragma unroll
    for (int j = 0; j < 8; ++j) { s += vv[j]; s2 += vv[j] * vv[j]; }
    #pragma unroll
    for (int d = 1; d < 64; d <<= 1) { s += __shfl_xor(s, d); s2 += __shfl_xor(s2, d); }
    float mean = s * (1.0f / 512.0f);
    float var  = s2 * (1.0f / 512.0f) - mean * mean;
    float rstd = rsqrtf(var + 1e-5f);
    int c = lane * 8;
    u16x8 o;
    #pragma unroll
    for (int j = 0; j < 8; ++j) o[j] = f2b((vv[j] - mean) * rstd * gam[c + j] + bet[c + j]);
    *(u16x8*)(O + (size_t)row * 512 + c) = o;
}

// ---- fused QKV GEMM: [8192,512] x Bt[1536,512]^T --------------------------
// blockIdx.y 0..11: seg = y>>2 (0:Q 1:K 2:V). V stored transposed.
__global__ __launch_bounds__(256) void gemm_qkv_k(
    const unsigned short* __restrict__ A, const unsigned short* __restrict__ Bt,
    const float* __restrict__ bq, const float* __restrict__ bk, const float* __restrict__ bv,
    unsigned short* __restrict__ Qo, unsigned short* __restrict__ Ko,
    unsigned short* __restrict__ VtO)
{
    __shared__ unsigned short Al[128][40];
    __shared__ unsigned short Bl[128][40];
    int tid = threadIdx.x;
    int wid = tid >> 6, lane = tid & 63;
    int lr = lane & 15, lg = lane >> 4;
    int m0 = blockIdx.x * 128, n0 = blockIdx.y * 128;
    int seg = blockIdx.y >> 2;
    int wr = (wid >> 1) * 64, wc = (wid & 1) * 64;
    f32x4 acc[4][4] = {};
    int ldr = tid >> 1;
    int ldc = (tid & 1) * 16;
    const unsigned short* Ap = A  + (size_t)(m0 + ldr) * 512 + ldc;
    const unsigned short* Bp = Bt + (size_t)(n0 + ldr) * 512 + ldc;
    for (int k0 = 0; k0 < 512; k0 += 32) {
        u16x8 a0 = *(const u16x8*)(Ap + k0);
        u16x8 a1 = *(const u16x8*)(Ap + k0 + 8);
        u16x8 b0 = *(const u16x8*)(Bp + k0);
        u16x8 b1 = *(const u16x8*)(Bp + k0 + 8);
        __syncthreads();
        *(u16x8*)&Al[ldr][ldc]     = a0;
        *(u16x8*)&Al[ldr][ldc + 8] = a1;
        *(u16x8*)&Bl[ldr][ldc]     = b0;
        *(u16x8*)&Bl[ldr][ldc + 8] = b1;
        __syncthreads();
        bf16x8 af[4], bfr[4];
        #pragma unroll
        for (int m = 0; m < 4; ++m) af[m]  = *(const bf16x8*)&Al[wr + m * 16 + lr][8 * lg];
        #pragma unroll
        for (int n = 0; n < 4; ++n) bfr[n] = *(const bf16x8*)&Bl[wc + n * 16 + lr][8 * lg];
        #pragma unroll
        for (int m = 0; m < 4; ++m)
            #pragma unroll
            for (int n = 0; n < 4; ++n)
                acc[m][n] = __builtin_amdgcn_mfma_f32_16x16x32_bf16(af[m], bfr[n], acc[m][n], 0, 0, 0);
    }
    const float* bb = seg == 0 ? bq : (seg == 1 ? bk : bv);
    unsigned short* dst = seg == 0 ? Qo : Ko;
    #pragma unroll
    for (int m = 0; m < 4; ++m)
      #pragma unroll
      for (int n = 0; n < 4; ++n) {
        int gr0 = m0 + wr + m * 16 + 4 * lg;
        int nc  = ((blockIdx.y & 3) << 7) + wc + n * 16 + lr;
        float bias = bb[nc];
        if (seg < 2) {
            #pragma unroll
            for (int j = 0; j < 4; ++j)
                dst[(size_t)(gr0 + j) * 512 + nc] = f2b(acc[m][n][j] + bias);
        } else {
            int bbk = gr0 >> 11, ss = gr0 & 2047, hh = nc >> 6, ee = nc & 63;
            ushort4 pv;
            pv.x = f2b(acc[m][n][0] + bias);
            pv.y = f2b(acc[m][n][1] + bias);
            pv.z = f2b(acc[m][n][2] + bias);
            pv.w = f2b(acc[m][n][3] + bias);
            *(ushort4*)&VtO[((size_t)((bbk * 8 + hh) * 64 + ee) << 11) + ss] = pv;
        }
      }
}

// ---- GEMM 128x64 tiles: C[8192,512] = A*Bt^T, fp32 epilogue ---------------
// MODE 2: C = f32(acc + bias + aux)   MODE 3: C = f32(relu(acc+bias) + aux)
template<int MODE>
__global__ __launch_bounds__(256) void gemm_n64_k(
    const unsigned short* __restrict__ A, const unsigned short* __restrict__ Bt,
    const float* __restrict__ bias, const float* __restrict__ aux,
    float* __restrict__ Cout)
{
    __shared__ unsigned short Al[128][40];
    __shared__ unsigned short Bl[64][40];
    int tid = threadIdx.x;
    int wid = tid >> 6, lane = tid & 63;
    int lr = lane & 15, lg = lane >> 4;
    int m0 = blockIdx.x * 128, n0 = blockIdx.y * 64;
    int wr = wid * 32;
    f32x4 acc[2][4] = {};
    int ldr = tid >> 1, ldc = (tid & 1) * 16;
    int brow = tid >> 2, bcol = (tid & 3) * 8;
    const unsigned short* Ap = A  + (size_t)(m0 + ldr) * 512 + ldc;
    const unsigned short* Bp = Bt + (size_t)(n0 + brow) * 512 + bcol;
    for (int k0 = 0; k0 < 512; k0 += 32) {
        u16x8 a0 = *(const u16x8*)(Ap + k0);
        u16x8 a1 = *(const u16x8*)(Ap + k0 + 8);
        u16x8 b0 = *(const u16x8*)(Bp + k0);
        __syncthreads();
        *(u16x8*)&Al[ldr][ldc]     = a0;
        *(u16x8*)&Al[ldr][ldc + 8] = a1;
        *(u16x8*)&Bl[brow][bcol]   = b0;
        __syncthreads();
        bf16x8 af[2], bfr[4];
        #pragma unroll
        for (int m = 0; m < 2; ++m) af[m]  = *(const bf16x8*)&Al[wr + m * 16 + lr][8 * lg];
        #pragma unroll
        for (int n = 0; n < 4; ++n) bfr[n] = *(const bf16x8*)&Bl[n * 16 + lr][8 * lg];
        #pragma unroll
        for (int m = 0; m < 2; ++m)
            #pragma unroll
            for (int n = 0; n < 4; ++n)
                acc[m][n] = __builtin_amdgcn_mfma_f32_16x16x32_bf16(af[m], bfr[n], acc[m][n], 0, 0, 0);
    }
    #pragma unroll
    for (int m = 0; m < 2; ++m)
      #pragma unroll
      for (int n = 0; n < 4; ++n)
        #pragma unroll
        for (int j = 0; j < 4; ++j) {
            int gr = m0 + wr + m * 16 + 4 * lg + j;
            int gc = n0 + n * 16 + lr;
            float v = acc[m][n][j] + bias[gc];
            if (MODE == 3) v = v > 0.0f ? v : 0.0f;
            Cout[(size_t)gr * 512 + gc] = v + aux[(size_t)gr * 512 + gc];
        }
}

// ---- flash attention, swapped-QK^T 32x32x16, KV-split wave pairs ----------
// Block = 4 waves. qsub = wid>>1 picks 32 q-rows, half = wid&1 picks KV half.
// Wave-pair merge of (m,l,O) through LDS at the end.
__global__ __launch_bounds__(256, 3) void attn3_k(
    const unsigned short* __restrict__ Q, const unsigned short* __restrict__ K,
    const unsigned short* __restrict__ Vt, unsigned short* __restrict__ O)
{
    __shared__ __align__(16) unsigned short Kl[2][4096];   // [half] 8 KB each
    __shared__ __align__(16) unsigned short Vl[2][4096];
    __shared__ float stats[2][2][32];                      // [qsub][{m,l}][q]

    const int tid  = threadIdx.x;
    const int lane = tid & 63;
    const int q31  = lane & 31;
    const int hi   = lane >> 5;
    const int wid  = tid >> 6;
    const int qsub = wid >> 1, half = wid & 1;

    // XCD swizzle: all 32 q-tiles of a (b,h) land on one XCD's L2
    int bid = blockIdx.x;
    int idx = bid >> 3;
    int bh  = (bid & 7) + 8 * (idx >> 5);
    int qt  = idx & 31;
    int b = bh >> 3, h = bh & 7;
    int q0 = qt * 64 + qsub * 32;

    const unsigned short* Qb = Q  + (size_t)b * 2048 * 512 + h * 64;
    const unsigned short* Kb = K  + (size_t)b * 2048 * 512 + h * 64;
    const unsigned short* Vb = Vt + (size_t)(b * 8 + h) * 64 * 2048;

    // Q B-frags, pre-scaled by 1/sqrt(dh) * log2(e)
    frag_u qf[4];
    const float qs = 0.125f * 1.44269504f;
    #pragma unroll
    for (int ds = 0; ds < 4; ++ds) {
        u16x8 raw = *(const u16x8*)(Qb + (size_t)(q0 + q31) * 512 + ds * 16 + hi * 8);
        #pragma unroll
        for (int i = 0; i < 4; ++i)
            qf[ds].u[i] = pack_bf16(b2f(raw[2 * i]) * qs, b2f(raw[2 * i + 1]) * qs);
    }

    // staging: wave stages one 64x64 u16 subtile (wid: 0=K0 1=K1 2=V0 3=V1);
    // lane stages tile-row `lane` (128 B = 8 segs)
    unsigned lws[8];
    #pragma unroll
    for (int s = 0; s < 8; ++s)
        lws[s] = (unsigned)((lane & 31) * 256 + (((lane >> 5) * 128 + s * 16) ^ ((lane & 15) << 4)));
    char* lbase = (char*)((wid & 2) ? &Vl[half][0] : &Kl[half][0]);
    const unsigned short* gp;
    int tmul;
    if (wid < 2) { gp = Kb + (size_t)(half * 1024 + lane) * 512; tmul = 512; }
    else         { gp = Vb + (size_t)lane * 2048 + half * 1024;  tmul = 1;   }

    u16x8 st[8];
    #pragma unroll
    for (int s = 0; s < 8; ++s) st[s] = *(const u16x8*)(gp + s * 8);

    f32x16 acc0, acc1;
    #pragma unroll
    for (int r = 0; r < 16; ++r) { acc0[r] = 0.0f; acc1[r] = 0.0f; }
    float m_run = -1e30f, l_run = 0.0f;
    const int swz = (q31 & 15) << 4;
    const char* Kh = (const char*)&Kl[half][0];
    const char* Vh = (const char*)&Vl[half][0];

    for (int it = 0; it < 16; ++it) {
        __syncthreads();
        #pragma unroll
        for (int s = 0; s < 8; ++s) *(u16x8*)(lbase + lws[s]) = st[s];
        __syncthreads();
        if (it < 15) {
            int t0n = (it + 1) * 64;
            #pragma unroll
            for (int s = 0; s < 8; ++s) st[s] = *(const u16x8*)(gp + (size_t)t0n * tmul + s * 8);
        }

        // S^T = K * Q^T (log2-scaled); s0: tokens 0..31 of tile, s1: 32..63
        f32x16 s0, s1;
        #pragma unroll
        for (int r = 0; r < 16; ++r) { s0[r] = 0.0f; s1[r] = 0.0f; }
        __builtin_amdgcn_s_setprio(1);
        #pragma unroll
        for (int ds = 0; ds < 4; ++ds) {
            bf16x8 k0 = *(const bf16x8*)(Kh + q31 * 256 + ((ds * 32 + hi * 16) ^ swz));
            bf16x8 k1 = *(const bf16x8*)(Kh + q31 * 256 + ((128 + ds * 32 + hi * 16) ^ swz));
            s0 = __builtin_amdgcn_mfma_f32_32x32x16_bf16(k0, qf[ds].v, s0, 0, 0, 0);
            s1 = __builtin_amdgcn_mfma_f32_32x32x16_bf16(k1, qf[ds].v, s1, 0, 0, 0);
        }
        __builtin_amdgcn_s_setprio(0);

        // tree max over 32 values + cross-half
        float mt[16];
        #pragma unroll
        for (int r = 0; r < 16; ++r) mt[r] = fmaxf(s0[r], s1[r]);
        #pragma unroll
        for (int d = 8; d >= 1; d >>= 1)
            #pragma unroll
            for (int r = 0; r < d; ++r) mt[r] = fmaxf(mt[r], mt[r + d]);
        float tmax = fmaxf(mt[0], __shfl_xor(mt[0], 32));

        if (__any(tmax > m_run + 11.0f)) {      // defer-max (T13)
            float mnew  = fmaxf(m_run, tmax);
            float alpha = exp2f(m_run - mnew);
            m_run = mnew;
            l_run *= alpha;
            #pragma unroll
            for (int r = 0; r < 16; ++r) {
                int cr = (r & 3) + 8 * (r >> 2) + 4 * hi;
                float ar = __shfl(alpha, cr);
                acc0[r] *= ar; acc1[r] *= ar;
            }
        }
        #pragma unroll
        for (int r = 0; r < 16; ++r) {
            s0[r] = exp2f(s0[r] - m_run);
            s1[r] = exp2f(s1[r] - m_run);
        }
        float at[16];
        #pragma unroll
        for (int r = 0; r < 16; ++r) at[r] = s0[r] + s1[r];
        #pragma unroll
        for (int d = 8; d >= 1; d >>= 1)
            #pragma unroll
            for (int r = 0; r < d; ++r) at[r] += at[r + d];
        l_run += at[0] + __shfl_xor(at[0], 32);

        // P C-frag -> A-frags in-register
        frag_u pa[4];
        #pragma unroll
        for (int g = 0; g < 2; ++g) {
            unsigned A0 = pack_bf16(s0[8 * g + 0], s0[8 * g + 1]);
            unsigned A1 = pack_bf16(s0[8 * g + 2], s0[8 * g + 3]);
            unsigned A2 = pack_bf16(s0[8 * g + 4], s0[8 * g + 5]);
            unsigned A3 = pack_bf16(s0[8 * g + 6], s0[8 * g + 7]);
            swap32(hi, A0, A2, pa[g].u[0], pa[g].u[2]);
            swap32(hi, A1, A3, pa[g].u[1], pa[g].u[3]);
            unsigned B0 = pack_bf16(s1[8 * g + 0], s1[8 * g + 1]);
            unsigned B1 = pack_bf16(s1[8 * g + 2], s1[8 * g + 3]);
            unsigned B2 = pack_bf16(s1[8 * g + 4], s1[8 * g + 5]);
            unsigned B3 = pack_bf16(s1[8 * g + 6], s1[8 * g + 7]);
            swap32(hi, B0, B2, pa[2 + g].u[0], pa[2 + g].u[2]);
            swap32(hi, B1, B3, pa[2 + g].u[1], pa[2 + g].u[3]);
        }

        __builtin_amdgcn_s_setprio(1);
        #pragma unroll
        for (int ks = 0; ks < 4; ++ks) {
            bf16x8 v0 = *(const bf16x8*)(Vh + q31 * 256 + ((ks * 32 + hi * 16) ^ swz));
            bf16x8 v1 = *(const bf16x8*)(Vh + q31 * 256 + ((128 + ks * 32 + hi * 16) ^ swz));
            acc0 = __builtin_amdgcn_mfma_f32_32x32x16_bf16(pa[ks].v, v0, acc0, 0, 0, 0);
            acc1 = __builtin_amdgcn_mfma_f32_32x32x16_bf16(pa[ks].v, v1, acc1, 0, 0, 0);
        }
        __builtin_amdgcn_s_setprio(0);
    }

    // ---- wave-pair merge through LDS (reuse Kl as fp32 buffer) ------------
    __syncthreads();
    float* aq = (float*)&Kl[0][0] + qsub * 2048;    // 8 KB per qsub
    if (half == 1) {
        #pragma unroll
        for (int u = 0; u < 8; ++u) {
            f32x4 t;
            if (u < 4) { t[0] = acc0[4*u]; t[1] = acc0[4*u+1]; t[2] = acc0[4*u+2]; t[3] = acc0[4*u+3]; }
            else       { int uu = u - 4;
                         t[0] = acc1[4*uu]; t[1] = acc1[4*uu+1]; t[2] = acc1[4*uu+2]; t[3] = acc1[4*uu+3]; }
            ((f32x4*)aq)[u * 64 + lane] = t;
        }
        if (lane < 32) { stats[qsub][0][lane] = m_run; stats[qsub][1][lane] = l_run; }
    }
    __syncthreads();
    if (half == 0) {
        float m1 = stats[qsub][0][q31], l1 = stats[qsub][1][q31];
        float ms = fmaxf(m_run, m1);
        float a0 = exp2f(m_run - ms), a1 = exp2f(m1 - ms);
        float li = 1.0f / (l_run * a0 + l1 * a1);
        float c0 = a0 * li, c1 = a1 * li;
        f32x4 oa[8];
        #pragma unroll
        for (int u = 0; u < 8; ++u) oa[u] = ((const f32x4*)aq)[u * 64 + lane];
        #pragma unroll
        for (int r = 0; r < 16; ++r) {
            int cr = (r & 3) + 8 * (r >> 2) + 4 * hi;
            float c0r = __shfl(c0, cr), c1r = __shfl(c1, cr);
            int u = r >> 2, e = r & 3;
            float o0 = acc0[r] * c0r + oa[u][e] * c1r;
            float o1 = acc1[r] * c0r + oa[4 + u][e] * c1r;
            size_t rowoff = (size_t)(b * 2048 + q0 + cr) * 512 + h * 64 + q31;
            O[rowoff]      = f2b(o0);
            O[rowoff + 32] = f2b(o1);
        }
    }
}

// ---------------------------------------------------------------------------
extern "C" void kernel_launch(void* const* d_in, const int* in_sizes, int n_in,
                              void* d_out, int out_size, void* d_ws, size_t ws_size,
                              hipStream_t stream)
{
    const float* x  = (const float*)d_in[0];
    const float* g1 = (const float*)d_in[1];
    const float* b1 = (const float*)d_in[2];
    const float* Wq = (const float*)d_in[3];
    const float* bq = (const float*)d_in[4];
    const float* Wk = (const float*)d_in[5];
    const float* bk = (const float*)d_in[6];
    const float* Wv = (const float*)d_in[7];
    const float* bv = (const float*)d_in[8];
    const float* Wm = (const float*)d_in[9];
    const float* bm = (const float*)d_in[10];
    const float* g2 = (const float*)d_in[11];
    const float* b2 = (const float*)d_in[12];
    const float* Wo = (const float*)d_in[13];
    const float* bo = (const float*)d_in[14];
    float* out = (float*)d_out;

    char* ws = (char*)d_ws;
    const size_t EB = (size_t)8192 * 512 * 2;
    unsigned short* h1  = (unsigned short*)(ws);
    unsigned short* qb  = (unsigned short*)(ws + EB);
    unsigned short* kb  = (unsigned short*)(ws + 2 * EB);
    unsigned short* vtb = (unsigned short*)(ws + 3 * EB);
    unsigned short* ao  = (unsigned short*)(ws + 4 * EB);
    unsigned short* h2  = (unsigned short*)(ws + 5 * EB);
    float*          hlp = (float*)(ws + 6 * EB);
    unsigned short* wqT = (unsigned short*)(ws + 8 * EB);   // QKV stacked [1536][512]
    unsigned short* wkT = wqT + 512 * 512;
    unsigned short* wvT = wkT + 512 * 512;
    unsigned short* wmT = wvT + 512 * 512;
    unsigned short* woT = wmT + 512 * 512;

    prep_weights_k<<<1024, 256, 0, stream>>>(Wq, Wk, Wv, Wm, Wo, wqT, wkT, wvT, wmT, woT);
    ln_bf16_k<<<8192, 64, 0, stream>>>(x, g1, b1, h1);
    gemm_qkv_k<<<dim3(64, 12), 256, 0, stream>>>(h1, wqT, bq, bk, bv, qb, kb, vtb);
    attn3_k<<<1024, 256, 0, stream>>>(qb, kb, vtb, ao);
    gemm_n64_k<2><<<dim3(64, 8), 256, 0, stream>>>(ao, wmT, bm, x, hlp);
    ln_bf16_k<<<8192, 64, 0, stream>>>(hlp, g2, b2, h2);
    gemm_n64_k<3><<<dim3(64, 8), 256, 0, stream>>>(h2, woT, bo, hlp, out);
}

// Round 4
// 159.924 us; speedup vs baseline: 1.5394x; 1.0377x over previous
//
#include <hip/hip_runtime.h>
#include <hip/hip_bf16.h>

// ---------------------------------------------------------------------------
// TrXL block on MI355X. bf16 MFMA everywhere, fp32 residual spine.
//   h1, Q, K, attn_out, h2 : bf16 [B*S=8192, 512]
//   Vt                     : bf16 [B, H, dh=64, S=2048]
//   h_ln_post              : fp32 [8192, 512]
//   weights prepped to Bt  : bf16 [N][K=512]  (QKV stacked to N=1536)
// attn4_k: swapped-QK^T 32x32x16 flash attn, dbuf LDS, 1 barrier/tile (T14).
// GEMMs: global_load_lds(16B) staging, linear LDS (m97 pattern).
// ---------------------------------------------------------------------------

typedef __attribute__((ext_vector_type(8))) short bf16x8;
typedef __attribute__((ext_vector_type(4))) float f32x4;
typedef __attribute__((ext_vector_type(16))) float f32x16;
typedef __attribute__((ext_vector_type(8))) unsigned short u16x8;

typedef union { bf16x8 v; unsigned u[4]; u16x8 s; } frag_u;

typedef const unsigned int __attribute__((address_space(1)))* gas_t;
typedef unsigned int __attribute__((address_space(3)))* las_t;
static __device__ __forceinline__ void glds16(const void* g, void* l) {
    __builtin_amdgcn_global_load_lds((gas_t)g, (las_t)l, 16, 0, 0);
}

static __device__ __forceinline__ unsigned short f2b(float f) {
    union { float f; unsigned u; } a; a.f = f;
    unsigned r = a.u + 0x7FFFu + ((a.u >> 16) & 1u);   // RNE
    return (unsigned short)(r >> 16);
}
static __device__ __forceinline__ float b2f(unsigned short u) {
    union { unsigned u; float f; } c; c.u = ((unsigned)u) << 16; return c.f;
}
static __device__ __forceinline__ unsigned pack_bf16(float lo, float hi) {
    __hip_bfloat162 p = __float22bfloat162_rn(make_float2(lo, hi));
    unsigned r; __builtin_memcpy(&r, &p, 4); return r;
}
static __device__ __forceinline__ void swap32(int hi, unsigned a, unsigned b,
                                              unsigned& x, unsigned& y) {
#if __has_builtin(__builtin_amdgcn_permlane32_swap)
    typedef __attribute__((ext_vector_type(2))) int i32x2;
    i32x2 r = __builtin_amdgcn_permlane32_swap((int)a, (int)b, false, false);
    x = (unsigned)r[0]; y = (unsigned)r[1];
#else
    unsigned ta = (unsigned)__shfl_xor((int)a, 32);
    unsigned tb = (unsigned)__shfl_xor((int)b, 32);
    x = hi ? tb : a;
    y = hi ? b : ta;
#endif
}

// ---- weight prep ----------------------------------------------------------
__global__ __launch_bounds__(256) void prep_weights_k(
    const float* __restrict__ Wq, const float* __restrict__ Wk, const float* __restrict__ Wv,
    const float* __restrict__ Wm, const float* __restrict__ Wo,
    unsigned short* __restrict__ wqT, unsigned short* __restrict__ wkT,
    unsigned short* __restrict__ wvT, unsigned short* __restrict__ wmT,
    unsigned short* __restrict__ woT)
{
    int idx = blockIdx.x * 256 + threadIdx.x;     // idx = n*512 + k
    int n = idx >> 9, k = idx & 511;
    int h = n >> 6, e = n & 63;
    size_t src_qkv = ((size_t)h * 512 + k) * 64 + e;
    wqT[idx] = f2b(Wq[src_qkv]);
    wkT[idx] = f2b(Wk[src_qkv]);
    wvT[idx] = f2b(Wv[src_qkv]);
    wmT[idx] = f2b(Wm[(size_t)k * 512 + n]);
    woT[idx] = f2b(Wo[(size_t)k * 512 + n]);
}

// ---- LayerNorm ------------------------------------------------------------
__global__ __launch_bounds__(64) void ln_bf16_k(
    const float* __restrict__ X, const float* __restrict__ gam,
    const float* __restrict__ bet, unsigned short* __restrict__ O)
{
    int row = blockIdx.x, lane = threadIdx.x;
    const float4* xr = (const float4*)(X + (size_t)row * 512);
    float4 v0 = xr[lane * 2], v1 = xr[lane * 2 + 1];
    float vv[8] = {v0.x, v0.y, v0.z, v0.w, v1.x, v1.y, v1.z, v1.w};
    float s = 0.f, s2 = 0.f;
    #pragma unroll
    for (int j = 0; j < 8; ++j) { s += vv[j]; s2 += vv[j] * vv[j]; }
    #pragma unroll
    for (int d = 1; d < 64; d <<= 1) { s += __shfl_xor(s, d); s2 += __shfl_xor(s2, d); }
    float mean = s * (1.0f / 512.0f);
    float var  = s2 * (1.0f / 512.0f) - mean * mean;
    float rstd = rsqrtf(var + 1e-5f);
    int c = lane * 8;
    u16x8 o;
    #pragma unroll
    for (int j = 0; j < 8; ++j) o[j] = f2b((vv[j] - mean) * rstd * gam[c + j] + bet[c + j]);
    *(u16x8*)(O + (size_t)row * 512 + c) = o;
}

// ---- fused QKV GEMM: [8192,512] x Bt[1536,512]^T, gload_lds staging -------
__global__ __launch_bounds__(256) void gemm_qkv_k(
    const unsigned short* __restrict__ A, const unsigned short* __restrict__ Bt,
    const float* __restrict__ bq, const float* __restrict__ bk, const float* __restrict__ bv,
    unsigned short* __restrict__ Qo, unsigned short* __restrict__ Ko,
    unsigned short* __restrict__ VtO)
{
    __shared__ unsigned short Al[128 * 32];   // linear [row][k], row = 64B
    __shared__ unsigned short Bl[128 * 32];
    int tid = threadIdx.x;
    int wid = tid >> 6, lane = tid & 63;
    int lr = lane & 15, lg = lane >> 4;
    int m0 = blockIdx.x * 128, n0 = blockIdx.y * 128;
    int seg = blockIdx.y >> 2;
    int wr = (wid >> 1) * 64, wc = (wid & 1) * 64;
    f32x4 acc[4][4] = {};
    // staging: wave covers rows [wid*32, wid*32+32); lane -> row +lane/4, seg (lane&3)*8
    const unsigned short* Ag = A  + (size_t)(m0 + wid * 32 + (lane >> 2)) * 512 + (lane & 3) * 8;
    const unsigned short* Bg = Bt + (size_t)(n0 + wid * 32 + (lane >> 2)) * 512 + (lane & 3) * 8;
    unsigned short* Alw = Al + wid * 32 * 32;
    unsigned short* Blw = Bl + wid * 32 * 32;
    for (int k0 = 0; k0 < 512; k0 += 32) {
        __syncthreads();
        glds16(Ag + k0,             Alw);
        glds16(Ag + k0 + 16 * 512,  Alw + 16 * 32);
        glds16(Bg + k0,             Blw);
        glds16(Bg + k0 + 16 * 512,  Blw + 16 * 32);
        __syncthreads();
        bf16x8 af[4], bfr[4];
        #pragma unroll
        for (int m = 0; m < 4; ++m) af[m]  = *(const bf16x8*)(Al + (wr + m * 16 + lr) * 32 + lg * 8);
        #pragma unroll
        for (int n = 0; n < 4; ++n) bfr[n] = *(const bf16x8*)(Bl + (wc + n * 16 + lr) * 32 + lg * 8);
        #pragma unroll
        for (int m = 0; m < 4; ++m)
            #pragma unroll
            for (int n = 0; n < 4; ++n)
                acc[m][n] = __builtin_amdgcn_mfma_f32_16x16x32_bf16(af[m], bfr[n], acc[m][n], 0, 0, 0);
    }
    const float* bb = seg == 0 ? bq : (seg == 1 ? bk : bv);
    unsigned short* dst = seg == 0 ? Qo : Ko;
    #pragma unroll
    for (int m = 0; m < 4; ++m)
      #pragma unroll
      for (int n = 0; n < 4; ++n) {
        int gr0 = m0 + wr + m * 16 + 4 * lg;
        int nc  = ((blockIdx.y & 3) << 7) + wc + n * 16 + lr;
        float bias = bb[nc];
        if (seg < 2) {
            #pragma unroll
            for (int j = 0; j < 4; ++j)
                dst[(size_t)(gr0 + j) * 512 + nc] = f2b(acc[m][n][j] + bias);
        } else {
            int bbk = gr0 >> 11, ss = gr0 & 2047, hh = nc >> 6, ee = nc & 63;
            ushort4 pv;
            pv.x = f2b(acc[m][n][0] + bias);
            pv.y = f2b(acc[m][n][1] + bias);
            pv.z = f2b(acc[m][n][2] + bias);
            pv.w = f2b(acc[m][n][3] + bias);
            *(ushort4*)&VtO[((size_t)((bbk * 8 + hh) * 64 + ee) << 11) + ss] = pv;
        }
      }
}

// ---- GEMM 128x64 tiles, gload_lds staging, fp32 epilogue ------------------
template<int MODE>
__global__ __launch_bounds__(256) void gemm_n64_k(
    const unsigned short* __restrict__ A, const unsigned short* __restrict__ Bt,
    const float* __restrict__ bias, const float* __restrict__ aux,
    float* __restrict__ Cout)
{
    __shared__ unsigned short Al[128 * 32];
    __shared__ unsigned short Bl[64 * 32];
    int tid = threadIdx.x;
    int wid = tid >> 6, lane = tid & 63;
    int lr = lane & 15, lg = lane >> 4;
    int m0 = blockIdx.x * 128, n0 = blockIdx.y * 64;
    int wr = wid * 32;
    f32x4 acc[2][4] = {};
    const unsigned short* Ag = A  + (size_t)(m0 + wid * 32 + (lane >> 2)) * 512 + (lane & 3) * 8;
    const unsigned short* Bg = Bt + (size_t)(n0 + wid * 16 + (lane >> 2)) * 512 + (lane & 3) * 8;
    unsigned short* Alw = Al + wid * 32 * 32;
    unsigned short* Blw = Bl + wid * 16 * 32;
    for (int k0 = 0; k0 < 512; k0 += 32) {
        __syncthreads();
        glds16(Ag + k0,            Alw);
        glds16(Ag + k0 + 16 * 512, Alw + 16 * 32);
        glds16(Bg + k0,            Blw);
        __syncthreads();
        bf16x8 af[2], bfr[4];
        #pragma unroll
        for (int m = 0; m < 2; ++m) af[m]  = *(const bf16x8*)(Al + (wr + m * 16 + lr) * 32 + lg * 8);
        #pragma unroll
        for (int n = 0; n < 4; ++n) bfr[n] = *(const bf16x8*)(Bl + (n * 16 + lr) * 32 + lg * 8);
        #pragma unroll
        for (int m = 0; m < 2; ++m)
            #pragma unroll
            for (int n = 0; n < 4; ++n)
                acc[m][n] = __builtin_amdgcn_mfma_f32_16x16x32_bf16(af[m], bfr[n], acc[m][n], 0, 0, 0);
    }
    #pragma unroll
    for (int m = 0; m < 2; ++m)
      #pragma unroll
      for (int n = 0; n < 4; ++n)
        #pragma unroll
        for (int j = 0; j < 4; ++j) {
            int gr = m0 + wr + m * 16 + 4 * lg + j;
            int gc = n0 + n * 16 + lr;
            float v = acc[m][n][j] + bias[gc];
            if (MODE == 3) v = v > 0.0f ? v : 0.0f;
            Cout[(size_t)gr * 512 + gc] = v + aux[(size_t)gr * 512 + gc];
        }
}

// ---- flash attention: 2 waves/block, dbuf LDS, 1 barrier/tile -------------
// wave = 32 q-rows; wave0 stages K-tile, wave1 stages V-tile (64 tok, 8 KB).
// K tile LDS: tok t,d -> row (t&31), byte ((t>>5)*128 + 2d) ^ ((t&15)<<4)
// V tile LDS: e,tok   -> row (e&31), byte ((e>>5)*128 + 2tok) ^ ((e&15)<<4)
__global__ __launch_bounds__(128, 2) void attn4_k(
    const unsigned short* __restrict__ Q, const unsigned short* __restrict__ K,
    const unsigned short* __restrict__ Vt, unsigned short* __restrict__ O)
{
    __shared__ __align__(16) unsigned short Kl[2][4096];   // dbuf, 8 KB each
    __shared__ __align__(16) unsigned short Vl[2][4096];

    const int tid  = threadIdx.x;
    const int lane = tid & 63;
    const int q31  = lane & 31;
    const int hi   = lane >> 5;
    const int wid  = tid >> 6;           // 0: K-stager, 1: V-stager

    // XCD swizzle: 32 q-blocks of one (b,h) share an XCD's L2
    int bid = blockIdx.x;
    int xcd = bid & 7, idx = bid >> 3;   // idx 0..127
    int bh  = xcd + 8 * (idx >> 5);      // 0..31
    int qt  = idx & 31;
    int b = bh >> 3, h = bh & 7;
    int q0 = qt * 64 + wid * 32;

    const unsigned short* Qb = Q  + (size_t)b * 2048 * 512 + h * 64;
    const unsigned short* Kb = K  + (size_t)b * 2048 * 512 + h * 64;
    const unsigned short* Vb = Vt + (size_t)(b * 8 + h) * 64 * 2048;

    // Q B-frags, pre-scaled by 1/sqrt(dh) * log2(e)
    frag_u qf[4];
    const float qs = 0.125f * 1.44269504f;
    #pragma unroll
    for (int ds = 0; ds < 4; ++ds) {
        u16x8 raw = *(const u16x8*)(Qb + (size_t)(q0 + q31) * 512 + ds * 16 + hi * 8);
        #pragma unroll
        for (int i = 0; i < 4; ++i)
            qf[ds].u[i] = pack_bf16(b2f(raw[2 * i]) * qs, b2f(raw[2 * i + 1]) * qs);
    }

    // staging: lane covers tile-row `lane` (128 B = 8 x 16B segs), swizzled
    unsigned lws[8];
    #pragma unroll
    for (int s = 0; s < 8; ++s)
        lws[s] = (unsigned)((lane & 31) * 256 + (((lane >> 5) * 128 + s * 16) ^ ((lane & 15) << 4)));

    u16x8 st[8];
    auto LOADT = [&](int t0) {
        if (wid == 0) {
            const unsigned short* p = Kb + (size_t)(t0 + lane) * 512;
            #pragma unroll
            for (int s = 0; s < 8; ++s) st[s] = *(const u16x8*)(p + s * 8);
        } else {
            const unsigned short* p = Vb + (size_t)lane * 2048 + t0;
            #pragma unroll
            for (int s = 0; s < 8; ++s) st[s] = *(const u16x8*)(p + s * 8);
        }
    };

    f32x16 acc0, acc1;
    #pragma unroll
    for (int r = 0; r < 16; ++r) { acc0[r] = 0.0f; acc1[r] = 0.0f; }
    float m_run = -1e30f, l_run = 0.0f;
    const int swz = (q31 & 15) << 4;

    // prologue: tile0 -> buf0; tile1 -> regs
    LOADT(0);
    {
        char* mb = (wid == 0) ? (char*)Kl[0] : (char*)Vl[0];
        #pragma unroll
        for (int s = 0; s < 8; ++s) *(u16x8*)(mb + lws[s]) = st[s];
    }
    LOADT(64);
    __syncthreads();

    int cur = 0;
    for (int it = 0; it < 32; ++it) {
        // write tile it+1 into buf cur^1 (overlaps with compute below)
        if (it < 31) {
            char* mb = (wid == 0) ? (char*)Kl[cur ^ 1] : (char*)Vl[cur ^ 1];
            #pragma unroll
            for (int s = 0; s < 8; ++s) *(u16x8*)(mb + lws[s]) = st[s];
        }
        if (it < 30) LOADT((it + 2) * 64);   // stays in flight across barrier (T14)

        const char* Kh = (const char*)Kl[cur];
        const char* Vh = (const char*)Vl[cur];

        // S^T = K * Q^T (log2-scaled); s0: tokens 0..31, s1: 32..63
        f32x16 s0, s1;
        #pragma unroll
        for (int r = 0; r < 16; ++r) { s0[r] = 0.0f; s1[r] = 0.0f; }
        __builtin_amdgcn_s_setprio(1);
        #pragma unroll
        for (int ds = 0; ds < 4; ++ds) {
            bf16x8 k0 = *(const bf16x8*)(Kh + q31 * 256 + ((ds * 32 + hi * 16) ^ swz));
            bf16x8 k1 = *(const bf16x8*)(Kh + q31 * 256 + ((128 + ds * 32 + hi * 16) ^ swz));
            s0 = __builtin_amdgcn_mfma_f32_32x32x16_bf16(k0, qf[ds].v, s0, 0, 0, 0);
            s1 = __builtin_amdgcn_mfma_f32_32x32x16_bf16(k1, qf[ds].v, s1, 0, 0, 0);
        }
        __builtin_amdgcn_s_setprio(0);

        // tree max + cross-half
        float mt[16];
        #pragma unroll
        for (int r = 0; r < 16; ++r) mt[r] = fmaxf(s0[r], s1[r]);
        #pragma unroll
        for (int d = 8; d >= 1; d >>= 1)
            #pragma unroll
            for (int r = 0; r < d; ++r) mt[r] = fmaxf(mt[r], mt[r + d]);
        float tmax = fmaxf(mt[0], __shfl_xor(mt[0], 32));

        if (__any(tmax > m_run + 11.0f)) {      // defer-max (T13)
            float mnew  = fmaxf(m_run, tmax);
            float alpha = exp2f(m_run - mnew);
            m_run = mnew;
            l_run *= alpha;
            #pragma unroll
            for (int r = 0; r < 16; ++r) {
                int cr = (r & 3) + 8 * (r >> 2) + 4 * hi;
                float ar = __shfl(alpha, cr);
                acc0[r] *= ar; acc1[r] *= ar;
            }
        }
        #pragma unroll
        for (int r = 0; r < 16; ++r) {
            s0[r] = exp2f(s0[r] - m_run);
            s1[r] = exp2f(s1[r] - m_run);
        }
        float at[16];
        #pragma unroll
        for (int r = 0; r < 16; ++r) at[r] = s0[r] + s1[r];
        #pragma unroll
        for (int d = 8; d >= 1; d >>= 1)
            #pragma unroll
            for (int r = 0; r < d; ++r) at[r] += at[r + d];
        l_run += at[0] + __shfl_xor(at[0], 32);

        // P C-frag -> A-frags in-register
        frag_u pa[4];
        #pragma unroll
        for (int g = 0; g < 2; ++g) {
            unsigned A0 = pack_bf16(s0[8 * g + 0], s0[8 * g + 1]);
            unsigned A1 = pack_bf16(s0[8 * g + 2], s0[8 * g + 3]);
            unsigned A2 = pack_bf16(s0[8 * g + 4], s0[8 * g + 5]);
            unsigned A3 = pack_bf16(s0[8 * g + 6], s0[8 * g + 7]);
            swap32(hi, A0, A2, pa[g].u[0], pa[g].u[2]);
            swap32(hi, A1, A3, pa[g].u[1], pa[g].u[3]);
            unsigned B0 = pack_bf16(s1[8 * g + 0], s1[8 * g + 1]);
            unsigned B1 = pack_bf16(s1[8 * g + 2], s1[8 * g + 3]);
            unsigned B2 = pack_bf16(s1[8 * g + 4], s1[8 * g + 5]);
            unsigned B3 = pack_bf16(s1[8 * g + 6], s1[8 * g + 7]);
            swap32(hi, B0, B2, pa[2 + g].u[0], pa[2 + g].u[2]);
            swap32(hi, B1, B3, pa[2 + g].u[1], pa[2 + g].u[3]);
        }

        __builtin_amdgcn_s_setprio(1);
        #pragma unroll
        for (int ks = 0; ks < 4; ++ks) {
            bf16x8 v0 = *(const bf16x8*)(Vh + q31 * 256 + ((ks * 32 + hi * 16) ^ swz));
            bf16x8 v1 = *(const bf16x8*)(Vh + q31 * 256 + ((128 + ks * 32 + hi * 16) ^ swz));
            acc0 = __builtin_amdgcn_mfma_f32_32x32x16_bf16(pa[ks].v, v0, acc0, 0, 0, 0);
            acc1 = __builtin_amdgcn_mfma_f32_32x32x16_bf16(pa[ks].v, v1, acc1, 0, 0, 0);
        }
        __builtin_amdgcn_s_setprio(0);

        __syncthreads();
        cur ^= 1;
    }

    float linv = 1.0f / l_run;
    #pragma unroll
    for (int r = 0; r < 16; ++r) {
        int cr = (r & 3) + 8 * (r >> 2) + 4 * hi;
        float li = __shfl(linv, cr);
        size_t rowoff = (size_t)(b * 2048 + q0 + cr) * 512 + h * 64 + q31;
        O[rowoff]      = f2b(acc0[r] * li);
        O[rowoff + 32] = f2b(acc1[r] * li);
    }
}

// ---------------------------------------------------------------------------
extern "C" void kernel_launch(void* const* d_in, const int* in_sizes, int n_in,
                              void* d_out, int out_size, void* d_ws, size_t ws_size,
                              hipStream_t stream)
{
    const float* x  = (const float*)d_in[0];
    const float* g1 = (const float*)d_in[1];
    const float* b1 = (const float*)d_in[2];
    const float* Wq = (const float*)d_in[3];
    const float* bq = (const float*)d_in[4];
    const float* Wk = (const float*)d_in[5];
    const float* bk = (const float*)d_in[6];
    const float* Wv = (const float*)d_in[7];
    const float* bv = (const float*)d_in[8];
    const float* Wm = (const float*)d_in[9];
    const float* bm = (const float*)d_in[10];
    const float* g2 = (const float*)d_in[11];
    const float* b2 = (const float*)d_in[12];
    const float* Wo = (const float*)d_in[13];
    const float* bo = (const float*)d_in[14];
    float* out = (float*)d_out;

    char* ws = (char*)d_ws;
    const size_t EB = (size_t)8192 * 512 * 2;
    unsigned short* h1  = (unsigned short*)(ws);
    unsigned short* qb  = (unsigned short*)(ws + EB);
    unsigned short* kb  = (unsigned short*)(ws + 2 * EB);
    unsigned short* vtb = (unsigned short*)(ws + 3 * EB);
    unsigned short* ao  = (unsigned short*)(ws + 4 * EB);
    unsigned short* h2  = (unsigned short*)(ws + 5 * EB);
    float*          hlp = (float*)(ws + 6 * EB);
    unsigned short* wqT = (unsigned short*)(ws + 8 * EB);   // QKV stacked [1536][512]
    unsigned short* wkT = wqT + 512 * 512;
    unsigned short* wvT = wkT + 512 * 512;
    unsigned short* wmT = wvT + 512 * 512;
    unsigned short* woT = wmT + 512 * 512;

    prep_weights_k<<<1024, 256, 0, stream>>>(Wq, Wk, Wv, Wm, Wo, wqT, wkT, wvT, wmT, woT);
    ln_bf16_k<<<8192, 64, 0, stream>>>(x, g1, b1, h1);
    gemm_qkv_k<<<dim3(64, 12), 256, 0, stream>>>(h1, wqT, bq, bk, bv, qb, kb, vtb);
    attn4_k<<<1024, 128, 0, stream>>>(qb, kb, vtb, ao);
    gemm_n64_k<2><<<dim3(64, 8), 256, 0, stream>>>(ao, wmT, bm, x, hlp);
    ln_bf16_k<<<8192, 64, 0, stream>>>(hlp, g2, b2, h2);
    gemm_n64_k<3><<<dim3(64, 8), 256, 0, stream>>>(h2, woT, bo, hlp, out);
}